// Round 4
// baseline (197.974 us; speedup 1.0000x reference)
//
#include <hip/hip_runtime.h>
#include <hip/hip_bf16.h>

// Block-sparse attention: B=2, S=4096, H=16, D=128, BS=64, LOCAL=8, GLOBAL=1.
// fp32 in/out, bf16 MFMA, flash online softmax (exp2 domain).
// This round: 2 q-blocks per workgroup (shared KV staging), improved Vt swizzle,
// Q pre-scaled at load.

typedef __bf16 bf16_t;
typedef bf16_t bf16x8 __attribute__((ext_vector_type(8)));
typedef bf16_t bf16x4 __attribute__((ext_vector_type(4)));
typedef float f32x4 __attribute__((ext_vector_type(4)));

#define BSZ 64
#define DIM 128
#define NH 16
#define SEQ 4096
#define ROWSTRIDE (NH * DIM)
#define KB_LD 136   // 272B rows -> QK B-frag reads bank-even

// Vt: linear [d=128][k=64] bf16. XOR-swizzle: fold d bits 2-4 (A bits 9-11)
// into 16B-chunk bits 4-6, plus d bit 1 (A bit 8) into bit 6 so the PV read
// (lanes vary lr = d low bits) spreads over 8 bank slots per 16-lane phase.
__device__ __forceinline__ uint32_t vt_swz(uint32_t A) {
    return A ^ (((A >> 9) & 7u) << 4) ^ (((A >> 8) & 1u) << 6);
}

__global__ __launch_bounds__(512, 4) void sparse_attn_kernel(
    const float* __restrict__ q, const float* __restrict__ k,
    const float* __restrict__ v, float* __restrict__ out)
{
    __shared__ __align__(16) bf16_t Kb[BSZ][KB_LD];
    __shared__ __align__(16) bf16_t Vt[DIM * BSZ];
    __shared__ __align__(16) bf16_t Pl[8][16][72];

    // 1024 wgs, 8 XCDs -> contiguous 128-chunk per XCD (bijective).
    const int L  = ((blockIdx.x & 7) << 7) | (blockIdx.x >> 3);
    const int g  = L & 31;          // q-block pair: blocks 2g, 2g+1
    const int h  = (L >> 5) & 15;
    const int b  = L >> 9;

    const int tid  = threadIdx.x;
    const int wave = tid >> 6;      // 0..7
    const int lane = tid & 63;
    const int lr = lane & 15;
    const int lk = lane >> 4;
    const int k0 = lk * 8;

    const int myblk = 2 * g + (wave >> 2);  // this wave's q-block (0..63)
    const int wq    = wave & 3;             // 16-row strip within q-block

    const int sc4 = tid & 31;   // staging: float4 column 0..31
    const int sr  = tid >> 5;   // staging: row group 0..15

    const float scale2 = 0.12751649736230476f;  // (1/sqrt(128)) * log2(e)

    const size_t bh_off = ((size_t)b * SEQ * NH + (size_t)h) * DIM;
    const float* kbh = k + bh_off;
    const float* vbh = v + bh_off;

    // ---- Q fragments, pre-scaled by scale2 (wave owns 16 rows of myblk) ----
    bf16x8 qf[4];
    {
        const float* qrow = q + bh_off + (size_t)(myblk * 64 + wq * 16 + lr) * ROWSTRIDE;
        #pragma unroll
        for (int kk = 0; kk < 4; ++kk) {
            const float4 a0 = *(const float4*)(qrow + 32 * kk + k0);
            const float4 a1 = *(const float4*)(qrow + 32 * kk + k0 + 4);
            bf16x8 f;
            f[0] = (bf16_t)(a0.x * scale2); f[1] = (bf16_t)(a0.y * scale2);
            f[2] = (bf16_t)(a0.z * scale2); f[3] = (bf16_t)(a0.w * scale2);
            f[4] = (bf16_t)(a1.x * scale2); f[5] = (bf16_t)(a1.y * scale2);
            f[6] = (bf16_t)(a1.z * scale2); f[7] = (bf16_t)(a1.w * scale2);
            qf[kk] = f;
        }
    }

    f32x4 oacc[8];
    #pragma unroll
    for (int n = 0; n < 8; ++n) oacc[n] = (f32x4){0.f, 0.f, 0.f, 0.f};
    float mrun[4], lrun[4];
    #pragma unroll
    for (int r = 0; r < 4; ++r) { mrun[r] = -3.0e38f; lrun[r] = 0.f; }

    // Union KV window of blocks {2g, 2g+1}: {0} U [lo, 2g+1]
    const int lo  = (2 * g - 7 > 1) ? (2 * g - 7) : 1;
    const int nit = 2 * g + 3 - lo;

    float4 kreg[4], vreg[4];

    #define LOAD_KV(jb)                                                          \
    {                                                                            \
        const float* kb_ = kbh + (size_t)((jb) * 64) * ROWSTRIDE + 4 * sc4;      \
        const float* vb_ = vbh + (size_t)((jb) * 64) * ROWSTRIDE + 4 * sc4;      \
        _Pragma("unroll")                                                        \
        for (int i = 0; i < 4; ++i)                                              \
            kreg[i] = *(const float4*)(kb_ + (size_t)(16 * i + sr) * ROWSTRIDE); \
        _Pragma("unroll")                                                        \
        for (int i = 0; i < 4; ++i)                                              \
            vreg[i] = *(const float4*)(vb_ + (size_t)(4 * sr + i) * ROWSTRIDE);  \
    }

    LOAD_KV(0);

    for (int t = 0; t < nit; ++t) {
        const int j = (t == 0) ? 0 : (lo + t - 1);

        // ---- regs -> LDS ----
        #pragma unroll
        for (int i = 0; i < 4; ++i) {
            const float4 t4 = kreg[i];
            bf16x4 c = {(bf16_t)t4.x, (bf16_t)t4.y, (bf16_t)t4.z, (bf16_t)t4.w};
            *(bf16x4*)&Kb[16 * i + sr][4 * sc4] = c;
        }
        #pragma unroll
        for (int j2 = 0; j2 < 4; ++j2) {
            const int d = 4 * sc4 + j2;
            bf16x4 c = {(bf16_t)((const float*)&vreg[0])[j2],
                        (bf16_t)((const float*)&vreg[1])[j2],
                        (bf16_t)((const float*)&vreg[2])[j2],
                        (bf16_t)((const float*)&vreg[3])[j2]};
            const uint32_t A = vt_swz((uint32_t)(d * 128 + 8 * sr));
            *(bf16x4*)((char*)Vt + A) = c;
        }
        __syncthreads();

        // ---- issue next block's loads (complete under compute) ----
        if (t + 1 < nit) { LOAD_KV(lo + t); }

        const bool act = (j == 0) || (j >= myblk - 7 && j <= myblk);
        if (act) {
            // ---- S = Q*K^T (16x64), already in exp2 domain ----
            f32x4 sacc[4];
            __builtin_amdgcn_s_setprio(1);
            #pragma unroll
            for (int n = 0; n < 4; ++n) {
                f32x4 a = (f32x4){0.f, 0.f, 0.f, 0.f};
                #pragma unroll
                for (int kk = 0; kk < 4; ++kk) {
                    bf16x8 kf = *(const bf16x8*)&Kb[16 * n + lr][32 * kk + k0];
                    a = __builtin_amdgcn_mfma_f32_16x16x32_bf16(qf[kk], kf, a, 0, 0, 0);
                }
                sacc[n] = a;
            }
            __builtin_amdgcn_s_setprio(0);

            // ---- mask (diag only) + row max ----
            float vmax[4];
            #pragma unroll
            for (int r = 0; r < 4; ++r) vmax[r] = -3.0e38f;
            if (j == myblk) {
                #pragma unroll
                for (int n = 0; n < 4; ++n)
                    #pragma unroll
                    for (int r = 0; r < 4; ++r) {
                        float s = sacc[n][r];
                        const int col  = 16 * n + lr;
                        const int rowq = wq * 16 + 4 * lk + r;
                        if (col > rowq) s = -1.0e30f;
                        sacc[n][r] = s;
                        vmax[r] = fmaxf(vmax[r], s);
                    }
            } else {
                #pragma unroll
                for (int n = 0; n < 4; ++n)
                    #pragma unroll
                    for (int r = 0; r < 4; ++r)
                        vmax[r] = fmaxf(vmax[r], sacc[n][r]);
            }
            #pragma unroll
            for (int r = 0; r < 4; ++r) {
                float m = vmax[r];
                m = fmaxf(m, __shfl_xor(m, 1));
                m = fmaxf(m, __shfl_xor(m, 2));
                m = fmaxf(m, __shfl_xor(m, 4));
                m = fmaxf(m, __shfl_xor(m, 8));
                vmax[r] = m;
            }

            // ---- online softmax (defer-max, THR=8 log2) ----
            bool defer = true;
            #pragma unroll
            for (int r = 0; r < 4; ++r) defer &= (vmax[r] - mrun[r] <= 8.0f);
            if (!__all(defer)) {
                #pragma unroll
                for (int r = 0; r < 4; ++r) {
                    const float mnew = fmaxf(mrun[r], vmax[r]);
                    const float alpha = exp2f(mrun[r] - mnew);
                    mrun[r] = mnew;
                    lrun[r] *= alpha;
                    #pragma unroll
                    for (int n = 0; n < 8; ++n) oacc[n][r] *= alpha;
                }
            }
            float rowsum[4];
            #pragma unroll
            for (int r = 0; r < 4; ++r) rowsum[r] = 0.f;
            #pragma unroll
            for (int n = 0; n < 4; ++n) {
                #pragma unroll
                for (int r = 0; r < 4; ++r) {
                    const float p = exp2f(sacc[n][r] - mrun[r]);
                    rowsum[r] += p;
                    Pl[wave][4 * lk + r][16 * n + lr] = (bf16_t)p;
                }
            }
            #pragma unroll
            for (int r = 0; r < 4; ++r) {
                float s = rowsum[r];
                s += __shfl_xor(s, 1);
                s += __shfl_xor(s, 2);
                s += __shfl_xor(s, 4);
                s += __shfl_xor(s, 8);
                lrun[r] += s;
            }

            // ---- O += P * V ----
            __builtin_amdgcn_s_setprio(1);
            #pragma unroll
            for (int n = 0; n < 8; ++n) {
                f32x4 a = oacc[n];
                #pragma unroll
                for (int kk = 0; kk < 2; ++kk) {
                    bf16x8 pf = *(const bf16x8*)&Pl[wave][lr][32 * kk + k0];
                    const uint32_t A = vt_swz((uint32_t)((16 * n + lr) * 128 + 64 * kk + 16 * lk));
                    bf16x8 vf = *(const bf16x8*)((const char*)Vt + A);
                    a = __builtin_amdgcn_mfma_f32_16x16x32_bf16(pf, vf, a, 0, 0, 0);
                }
                oacc[n] = a;
            }
            __builtin_amdgcn_s_setprio(0);
        }
        __syncthreads();
    }

    // ---- epilogue ----
    float* obase = out + bh_off + (size_t)(myblk * 64 + wq * 16) * ROWSTRIDE;
    #pragma unroll
    for (int r = 0; r < 4; ++r) {
        const float inv = 1.0f / lrun[r];
        float* orow = obase + (size_t)(4 * lk + r) * ROWSTRIDE;
        #pragma unroll
        for (int n = 0; n < 8; ++n) {
            orow[16 * n + lr] = oacc[n][r] * inv;
        }
    }
}

extern "C" void kernel_launch(void* const* d_in, const int* in_sizes, int n_in,
                              void* d_out, int out_size, void* d_ws, size_t ws_size,
                              hipStream_t stream) {
    const float* q = (const float*)d_in[0];
    const float* k = (const float*)d_in[1];
    const float* v = (const float*)d_in[2];
    float* out = (float*)d_out;
    sparse_attn_kernel<<<dim3(1024), dim3(512), 0, stream>>>(q, k, v, out);
}